// Round 1
// baseline (4441.540 us; speedup 1.0000x reference)
//
#include <hip/hip_runtime.h>
#include <cstdio>
#include <cstdint>

// ---------- types / helpers ----------
typedef __attribute__((ext_vector_type(8))) short short8;   // 8 bf16 (4 VGPRs)
typedef __attribute__((ext_vector_type(4))) float f32x4;    // MFMA 16x16 acc

__device__ __forceinline__ f32x4 MFMA16(short8 a, short8 b, f32x4 c) {
  return __builtin_amdgcn_mfma_f32_16x16x32_bf16(a, b, c, 0, 0, 0);
}
__device__ __forceinline__ float bf2f(uint16_t u) {
  union { uint32_t u; float f; } v; v.u = ((uint32_t)u) << 16; return v.f;
}
__device__ __forceinline__ uint16_t f2bf(float f) {
  union { float f; uint32_t u; } v; v.f = f;
  uint32_t r = v.u + 0x7fffu + ((v.u >> 16) & 1u);  // RNE
  return (uint16_t)(r >> 16);
}
__device__ __forceinline__ float fsig(float x) { return 1.0f / (1.0f + __expf(-x)); }
__device__ __forceinline__ float ftanh_(float x) { return 2.0f / (1.0f + __expf(-2.0f * x)) - 1.0f; }

// Problem dims
// B=128 S=256 L=16, EMB=256 HID=512, CEMB=64 CHID=128, NCLS=20
// word rows n = t*128 + b  (matches x_chars.reshape(S*B, L))

// ---------- ws layout (bytes) ----------
#define OFF_CWI   0u            // char_Wi bf16 [384][64]
#define OFF_CWH   49152u        // char_Wh bf16 [384][128]
#define OFF_GWI   147456u       // gru_Wi  bf16 [1536][384]
#define OFF_GWH   1327104u      // gru_Wh  bf16 [1536][512]
#define OFF_CEMB  2899968u      // char_emb bf16 [128][64]
#define OFF_CRZ   2916352u      // f32 [256]  char bi+bh (r,z)
#define OFF_CNI   2917376u      // f32 [128]  char bi (n)
#define OFF_CNH   2917888u      // f32 [128]  char bh (n)
#define OFF_WRZ   2918400u      // f32 [1024] gru bi+bh (r,z)
#define OFF_WNI   2922496u      // f32 [512]  gru bi (n)
#define OFF_WNH   2924544u      // f32 [512]  gru bh (n)
#define OFF_CNT   2926592u      // barrier counter
#define OFF_FEATS 3145728u      // bf16 [32768][384]
#define OFF_XW    28311552u     // bf16 [32768][1536]
#define OFF_H     128974848u    // bf16 [32768][512]  (= [256][128][512])
#define WS_NEEDED 145752064ull

// ---------- K0: weight convert + bias fuse + counter zero ----------
__global__ void k_prep(const float* __restrict__ cWi, const float* __restrict__ cWh,
                       const float* __restrict__ gWi, const float* __restrict__ gWh,
                       const float* __restrict__ cemb,
                       const float* __restrict__ cbi, const float* __restrict__ cbh,
                       const float* __restrict__ gbi, const float* __restrict__ gbh,
                       uint16_t* o_cWi, uint16_t* o_cWh, uint16_t* o_gWi, uint16_t* o_gWh,
                       uint16_t* o_cemb, float* o_crz, float* o_cni, float* o_cnh,
                       float* o_wrz, float* o_wni, float* o_wnh, unsigned* cnt)
{
  int g = blockIdx.x * 256 + threadIdx.x;
  int st = gridDim.x * 256;
  for (int i = g; i < 24576;  i += st) o_cWi[i] = f2bf(cWi[i]);
  for (int i = g; i < 49152;  i += st) o_cWh[i] = f2bf(cWh[i]);
  for (int i = g; i < 589824; i += st) o_gWi[i] = f2bf(gWi[i]);
  for (int i = g; i < 786432; i += st) o_gWh[i] = f2bf(gWh[i]);
  for (int i = g; i < 8192;   i += st) o_cemb[i] = f2bf(cemb[i]);
  for (int i = g; i < 256;  i += st) o_crz[i] = cbi[i] + cbh[i];
  for (int i = g; i < 128;  i += st) { o_cni[i] = cbi[256 + i]; o_cnh[i] = cbh[256 + i]; }
  for (int i = g; i < 1024; i += st) o_wrz[i] = gbi[i] + gbh[i];
  for (int i = g; i < 512;  i += st) { o_wni[i] = gbi[1024 + i]; o_wnh[i] = gbh[1024 + i]; }
  if (g == 0) *cnt = 0u;
}

// ---------- K2: word embedding gather -> feats[:, 0:256] ----------
__global__ void k_emb(const int* __restrict__ x, const float* __restrict__ embw,
                      uint16_t* __restrict__ feats)
{
  int n = blockIdx.x * 4 + (threadIdx.x >> 6);   // word row, n = t*128 + b
  int lane = threadIdx.x & 63;
  int t = n >> 7, b = n & 127;
  int wid = x[b * 256 + t];
  float4 v = *(const float4*)(embw + (size_t)wid * 256 + lane * 4);
  uint16_t* dst = feats + (size_t)n * 384 + lane * 4;
  dst[0] = f2bf(v.x); dst[1] = f2bf(v.y); dst[2] = f2bf(v.z); dst[3] = f2bf(v.w);
}

// ---------- K1: char GRU (batch-parallel, MFMA) -> feats[:, 256:384] ----------
// Grid 512 x 256 thr (4 waves, 16 words/wave). LDS: Wh[384][136] + ids[64][17] + h[64][136]
__global__ __launch_bounds__(256, 1) void k_char(
    const int* __restrict__ xch, const uint16_t* __restrict__ cembw,
    const uint16_t* __restrict__ cWi, const uint16_t* __restrict__ cWh,
    const float* __restrict__ crz, const float* __restrict__ cni,
    const float* __restrict__ cnh, uint16_t* __restrict__ feats)
{
  extern __shared__ char lds[];
  uint16_t* WhL = (uint16_t*)lds;                    // [384][136] bf16, 104448 B
  int*      idsL = (int*)(lds + 104448);             // [64][17], 4352 B
  uint16_t* hL  = (uint16_t*)(lds + 104448 + 4352);  // [64][136], 17408 B
  const int tid = threadIdx.x;
  const int wbase = blockIdx.x * 64;

  for (int i = tid; i < 384 * 16; i += 256) {
    int row = i >> 4, ch = i & 15;
    *(uint4*)(WhL + row * 136 + ch * 8) = *(const uint4*)(cWh + row * 128 + ch * 8);
  }
  for (int i = tid; i < 64 * 16; i += 256) {
    int w0 = i >> 4, p = i & 15;
    idsL[w0 * 17 + p] = xch[(wbase + w0) * 16 + p];
  }
  for (int i = tid; i < 64 * 136 / 2; i += 256) ((unsigned*)hL)[i] = 0u;
  __syncthreads();

  const int wv = tid >> 6, lane = tid & 63;
  const int q = lane >> 4, c = lane & 15;
  float br_[8], bz_[8], bni_[8], bnh_[8];
#pragma unroll
  for (int jb = 0; jb < 8; ++jb) {
    int j = jb * 16 + c;
    br_[jb] = crz[j]; bz_[jb] = crz[128 + j]; bni_[jb] = cni[j]; bnh_[jb] = cnh[j];
  }
  const int lwA = wv * 16 + c;        // word row for A-operand (m = lane&15)
  const int lwD = wv * 16 + q * 4;    // D rows base (+reg)

  for (int t = 0; t < 16; ++t) {
    f32x4 aRZ[16], aXN[8], aGN[8];
#pragma unroll
    for (int i = 0; i < 16; ++i) aRZ[i] = (f32x4)0.0f;
#pragma unroll
    for (int i = 0; i < 8; ++i) { aXN[i] = (f32x4)0.0f; aGN[i] = (f32x4)0.0f; }

    // xw contribution: cemb[word,t,:] @ Wi^T   (K=64)
    int id = idsL[lwA * 17 + t];
    const uint16_t* cerow = cembw + id * 64;
    short8 Ae0 = *(const short8*)(cerow + q * 8);
    short8 Ae1 = *(const short8*)(cerow + 32 + q * 8);
#pragma unroll
    for (int tl = 0; tl < 24; ++tl) {
      const uint16_t* wr = cWi + (tl * 16 + c) * 64 + q * 8;
      short8 B0 = *(const short8*)(wr);
      short8 B1 = *(const short8*)(wr + 32);
      if (tl < 16) { aRZ[tl] = MFMA16(Ae0, B0, aRZ[tl]); aRZ[tl] = MFMA16(Ae1, B1, aRZ[tl]); }
      else { aXN[tl - 16] = MFMA16(Ae0, B0, aXN[tl - 16]); aXN[tl - 16] = MFMA16(Ae1, B1, aXN[tl - 16]); }
    }
    // gh contribution: h @ Wh^T   (K=128); h=0 at t=0 is harmless
    short8 Ah[4];
#pragma unroll
    for (int kt = 0; kt < 4; ++kt) Ah[kt] = *(const short8*)(hL + lwA * 136 + kt * 32 + q * 8);
#pragma unroll
    for (int tl = 0; tl < 24; ++tl) {
#pragma unroll
      for (int kt = 0; kt < 4; ++kt) {
        short8 Bw = *(const short8*)(WhL + (tl * 16 + c) * 136 + kt * 32 + q * 8);
        if (tl < 16) aRZ[tl] = MFMA16(Ah[kt], Bw, aRZ[tl]);
        else aGN[tl - 16] = MFMA16(Ah[kt], Bw, aGN[tl - 16]);
      }
    }
    // gates + h update (f32)
#pragma unroll
    for (int jb = 0; jb < 8; ++jb) {
      int j = jb * 16 + c;
#pragma unroll
      for (int rg = 0; rg < 4; ++rg) {
        float r = fsig(aRZ[jb][rg] + br_[jb]);
        float z = fsig(aRZ[8 + jb][rg] + bz_[jb]);
        float n = ftanh_(aXN[jb][rg] + bni_[jb] + r * (aGN[jb][rg] + bnh_[jb]));
        int hoff = (lwD + rg) * 136 + j;
        float hold = bf2f(hL[hoff]);
        hL[hoff] = f2bf((1.0f - z) * n + z * hold);
      }
    }
  }
  __syncthreads();
  for (int i = tid; i < 64 * 128; i += 256) {
    int w0 = i >> 7, col = i & 127;
    feats[(size_t)(wbase + w0) * 384 + 256 + col] = hL[w0 * 136 + col];
  }
}

// ---------- K3: xw = feats @ gru_Wi^T  (M=32768, N=1536, K=384) ----------
__global__ __launch_bounds__(256) void k_gemm_xw(
    const uint16_t* __restrict__ A, const uint16_t* __restrict__ Bm,
    uint16_t* __restrict__ C)
{
  __shared__ uint16_t AL[128 * 40];
  __shared__ uint16_t BL[128 * 40];
  const int tid = threadIdx.x;
  const int bm = blockIdx.x & 255, bn = blockIdx.x >> 8;
  const int m0 = bm * 128, n0 = bn * 128;
  const int wv = tid >> 6, lane = tid & 63, q = lane >> 4, c = lane & 15;
  const int vm = (wv >> 1) * 64, vn = (wv & 1) * 64;
  f32x4 acc[4][4];
#pragma unroll
  for (int mt = 0; mt < 4; ++mt)
#pragma unroll
    for (int nt = 0; nt < 4; ++nt) acc[mt][nt] = (f32x4)0.0f;

  for (int k0 = 0; k0 < 384; k0 += 32) {
    __syncthreads();
    for (int i2 = tid; i2 < 512; i2 += 256) {
      int row = i2 >> 2, cc = i2 & 3;
      *(uint4*)(AL + row * 40 + cc * 8) = *(const uint4*)(A + (size_t)(m0 + row) * 384 + k0 + cc * 8);
      *(uint4*)(BL + row * 40 + cc * 8) = *(const uint4*)(Bm + (size_t)(n0 + row) * 384 + k0 + cc * 8);
    }
    __syncthreads();
    short8 af[4], bfr[4];
#pragma unroll
    for (int mt = 0; mt < 4; ++mt) af[mt] = *(const short8*)(AL + (vm + mt * 16 + c) * 40 + q * 8);
#pragma unroll
    for (int nt = 0; nt < 4; ++nt) bfr[nt] = *(const short8*)(BL + (vn + nt * 16 + c) * 40 + q * 8);
#pragma unroll
    for (int mt = 0; mt < 4; ++mt)
#pragma unroll
      for (int nt = 0; nt < 4; ++nt) acc[mt][nt] = MFMA16(af[mt], bfr[nt], acc[mt][nt]);
  }
#pragma unroll
  for (int mt = 0; mt < 4; ++mt)
#pragma unroll
    for (int nt = 0; nt < 4; ++nt)
#pragma unroll
      for (int rg = 0; rg < 4; ++rg) {
        int m = m0 + vm + mt * 16 + q * 4 + rg;
        int n = n0 + vn + nt * 16 + c;
        C[(size_t)m * 1536 + n] = f2bf(acc[mt][nt][rg]);
      }
}

// ---------- K4: word GRU, persistent, 128 WGs x 64 thr, hand grid barrier ----------
// WG (gb,gc): batches [gb*16, +16), hidden cols [gc*32, +32). LDS Wh slice [96][520] bf16.
__global__ __launch_bounds__(64, 1) void k_gru(
    const uint16_t* __restrict__ xw, const uint16_t* __restrict__ gWh,
    const float* __restrict__ wrz, const float* __restrict__ wni,
    const float* __restrict__ wnh, uint16_t* __restrict__ H,
    unsigned* __restrict__ cnt)
{
  extern __shared__ char lds[];
  uint16_t* WhL = (uint16_t*)lds;   // [96][520] = 99840 B
  const int tid = threadIdx.x;
  const int gb = blockIdx.x >> 4, gc = blockIdx.x & 15;
  const int m0 = gb * 16, j0 = gc * 32;
  for (int i = tid; i < 96 * 64; i += 64) {
    int row = i >> 6, ch = i & 63;
    int gr = (row < 32) ? (j0 + row) : (row < 64) ? (512 + j0 + row - 32) : (1024 + j0 + row - 64);
    *(uint4*)(WhL + row * 520 + ch * 8) = *(const uint4*)(gWh + (size_t)gr * 512 + ch * 8);
  }
  const int q = tid >> 4, c = tid & 15;
  const int j1 = j0 + c, j2 = j0 + 16 + c;
  const float br0 = wrz[j1], br1 = wrz[j2];
  const float bz0 = wrz[512 + j1], bz1 = wrz[512 + j2];
  const float bi0 = wni[j1], bi1 = wni[j2];
  const float bh0 = wnh[j1], bh1 = wnh[j2];
  __syncthreads();

  for (int t = 0; t < 256; ++t) {
    const uint16_t* xwt = xw + (size_t)(t * 128 + m0) * 1536;
    f32x4 acc[6];
#pragma unroll
    for (int rg = 0; rg < 4; ++rg) {
      const uint16_t* rowp = xwt + (q * 4 + rg) * 1536;
      acc[0][rg] = bf2f(rowp[j1]);
      acc[1][rg] = bf2f(rowp[j2]);
      acc[2][rg] = bf2f(rowp[512 + j1]);
      acc[3][rg] = bf2f(rowp[512 + j2]);
      acc[4][rg] = 0.0f; acc[5][rg] = 0.0f;
    }
    if (t > 0) {
      const uint16_t* hp = H + (size_t)((t - 1) * 128 + m0) * 512 + c * 512;
#pragma unroll 4
      for (int kt = 0; kt < 16; ++kt) {
        short8 a = *(const short8*)(hp + kt * 32 + q * 8);
#pragma unroll
        for (int tl = 0; tl < 6; ++tl) {
          short8 b = *(const short8*)(WhL + (tl * 16 + c) * 520 + kt * 32 + q * 8);
          acc[tl] = MFMA16(a, b, acc[tl]);
        }
      }
    }
    const uint16_t* hprev = H + (size_t)(((t > 0 ? t : 1) - 1) * 128 + m0) * 512;
    uint16_t* hcur = H + (size_t)(t * 128 + m0) * 512;
#pragma unroll
    for (int rg = 0; rg < 4; ++rg) {
      int m = q * 4 + rg;
      const uint16_t* xr = xwt + m * 1536;
      float r0 = fsig(acc[0][rg] + br0);
      float z0 = fsig(acc[2][rg] + bz0);
      float n0 = ftanh_(bf2f(xr[1024 + j1]) + bi0 + r0 * (acc[4][rg] + bh0));
      float h0 = (t > 0) ? bf2f(hprev[m * 512 + j1]) : 0.0f;
      hcur[m * 512 + j1] = f2bf((1.0f - z0) * n0 + z0 * h0);
      float r1 = fsig(acc[1][rg] + br1);
      float z1 = fsig(acc[3][rg] + bz1);
      float n1 = ftanh_(bf2f(xr[1024 + j2]) + bi1 + r1 * (acc[5][rg] + bh1));
      float h1 = (t > 0) ? bf2f(hprev[m * 512 + j2]) : 0.0f;
      hcur[m * 512 + j2] = f2bf((1.0f - z1) * n1 + z1 * h1);
    }
    // ---- grid barrier: flush, arrive (64 adds/WG -> coalesced), spin, acquire ----
    __threadfence();
    __hip_atomic_fetch_add(cnt, 1u, __ATOMIC_RELAXED, __HIP_MEMORY_SCOPE_AGENT);
    const unsigned target = (unsigned)(t + 1) * 8192u;  // 128 WGs * 64 lanes
    int spins = 0;
    while (__hip_atomic_load(cnt, __ATOMIC_RELAXED, __HIP_MEMORY_SCOPE_AGENT) < target) {
      __builtin_amdgcn_s_sleep(2);
      if (++spins > 200000) break;   // safety: wrong-but-terminating beats deadlock
    }
    __threadfence();
  }
}

// ---------- K5: classifier pred[b,t,c] = H[t,b,:] . cls_W[c,:] + cls_b[c] ----------
__global__ void k_cls(const uint16_t* __restrict__ H, const float* __restrict__ W,
                      const float* __restrict__ bb, float* __restrict__ out)
{
  int g = blockIdx.x * 256 + threadIdx.x;   // 655360 = 32768 rows * 20
  int c = g % 20, row = g / 20;
  int t = row >> 7, b = row & 127;
  const uint16_t* hp = H + (size_t)row * 512;
  const float* wp = W + c * 512;
  float acc = 0.0f;
  for (int i = 0; i < 512; i += 8) {
    uint4 hv = *(const uint4*)(hp + i);
    float4 w0 = *(const float4*)(wp + i);
    float4 w1 = *(const float4*)(wp + i + 4);
    acc += bf2f((uint16_t)hv.x) * w0.x + bf2f((uint16_t)(hv.x >> 16)) * w0.y
         + bf2f((uint16_t)hv.y) * w0.z + bf2f((uint16_t)(hv.y >> 16)) * w0.w
         + bf2f((uint16_t)hv.z) * w1.x + bf2f((uint16_t)(hv.z >> 16)) * w1.y
         + bf2f((uint16_t)hv.w) * w1.z + bf2f((uint16_t)(hv.w >> 16)) * w1.w;
  }
  out[((size_t)b * 256 + t) * 20 + c] = acc + bb[c];
}

// ---------- launch ----------
extern "C" void kernel_launch(void* const* d_in, const int* in_sizes, int n_in,
                              void* d_out, int out_size, void* d_ws, size_t ws_size,
                              hipStream_t stream) {
  (void)in_sizes; (void)n_in; (void)out_size;
  const int*   x     = (const int*)d_in[0];
  const int*   xch   = (const int*)d_in[1];
  const float* embw  = (const float*)d_in[2];
  const float* cembw = (const float*)d_in[3];
  const float* cWi   = (const float*)d_in[4];
  const float* cWh   = (const float*)d_in[5];
  const float* cbi   = (const float*)d_in[6];
  const float* cbh   = (const float*)d_in[7];
  const float* gWi   = (const float*)d_in[8];
  const float* gWh   = (const float*)d_in[9];
  const float* gbi   = (const float*)d_in[10];
  const float* gbh   = (const float*)d_in[11];
  const float* clsW  = (const float*)d_in[12];
  const float* clsb  = (const float*)d_in[13];
  float* out = (float*)d_out;
  char* w = (char*)d_ws;

  if (ws_size < WS_NEEDED) { fprintf(stderr, "ws too small: %zu < %llu\n", ws_size, WS_NEEDED); return; }

  uint16_t* o_cWi  = (uint16_t*)(w + OFF_CWI);
  uint16_t* o_cWh  = (uint16_t*)(w + OFF_CWH);
  uint16_t* o_gWi  = (uint16_t*)(w + OFF_GWI);
  uint16_t* o_gWh  = (uint16_t*)(w + OFF_GWH);
  uint16_t* o_cemb = (uint16_t*)(w + OFF_CEMB);
  float* crz = (float*)(w + OFF_CRZ);
  float* cni = (float*)(w + OFF_CNI);
  float* cnh = (float*)(w + OFF_CNH);
  float* wrz = (float*)(w + OFF_WRZ);
  float* wni = (float*)(w + OFF_WNI);
  float* wnh = (float*)(w + OFF_WNH);
  unsigned* cnt = (unsigned*)(w + OFF_CNT);
  uint16_t* feats = (uint16_t*)(w + OFF_FEATS);
  uint16_t* xwb   = (uint16_t*)(w + OFF_XW);
  uint16_t* Hb    = (uint16_t*)(w + OFF_H);

  // >64KB dynamic LDS kernels need the attribute; idempotent, host-side only.
  (void)hipFuncSetAttribute((const void*)k_char, hipFuncAttributeMaxDynamicSharedMemorySize, 126208);
  (void)hipFuncSetAttribute((const void*)k_gru,  hipFuncAttributeMaxDynamicSharedMemorySize, 99840);

  k_prep<<<512, 256, 0, stream>>>(cWi, cWh, gWi, gWh, cembw, cbi, cbh, gbi, gbh,
                                  o_cWi, o_cWh, o_gWi, o_gWh, o_cemb,
                                  crz, cni, cnh, wrz, wni, wnh, cnt);
  k_emb<<<8192, 256, 0, stream>>>(x, embw, feats);
  k_char<<<512, 256, 126208, stream>>>(xch, o_cemb, o_cWi, o_cWh, crz, cni, cnh, feats);
  k_gemm_xw<<<3072, 256, 0, stream>>>(feats, o_gWi, xwb);
  k_gru<<<128, 64, 99840, stream>>>(xwb, o_gWh, wrz, wni, wnh, Hb, cnt);
  k_cls<<<2560, 256, 0, stream>>>(Hb, clsW, clsb, out);
}

// Round 2
// 3415.783 us; speedup vs baseline: 1.3003x; 1.3003x over previous
//
#include <hip/hip_runtime.h>
#include <cstdio>
#include <cstdint>

// ---------- types / helpers ----------
typedef __attribute__((ext_vector_type(8))) short short8;   // 8 bf16 (4 VGPRs)
typedef __attribute__((ext_vector_type(4))) float f32x4;    // MFMA 16x16 acc

__device__ __forceinline__ f32x4 MFMA16(short8 a, short8 b, f32x4 c) {
  return __builtin_amdgcn_mfma_f32_16x16x32_bf16(a, b, c, 0, 0, 0);
}
__device__ __forceinline__ float bf2f(uint16_t u) {
  union { uint32_t u; float f; } v; v.u = ((uint32_t)u) << 16; return v.f;
}
__device__ __forceinline__ uint16_t f2bf(float f) {
  union { float f; uint32_t u; } v; v.f = f;
  uint32_t r = v.u + 0x7fffu + ((v.u >> 16) & 1u);  // RNE
  return (uint16_t)(r >> 16);
}
__device__ __forceinline__ float fsig(float x) { return 1.0f / (1.0f + __expf(-x)); }
__device__ __forceinline__ float ftanh_(float x) { return 2.0f / (1.0f + __expf(-2.0f * x)) - 1.0f; }

// Problem dims
// B=128 S=256 L=16, EMB=256 HID=512, CEMB=64 CHID=128, NCLS=20
// word rows n = t*128 + b  (matches x_chars.reshape(S*B, L))

// ---------- ws layout (bytes) ----------
#define OFF_CWI   0u            // char_Wi bf16 [384][64]
#define OFF_CWH   49152u        // char_Wh bf16 [384][128]
#define OFF_GWI   147456u       // gru_Wi  bf16 [1536][384]
#define OFF_GWH   1327104u      // gru_Wh  bf16 [1536][512]
#define OFF_CEMB  2899968u      // char_emb bf16 [128][64]
#define OFF_CRZ   2916352u      // f32 [256]  char bi+bh (r,z)
#define OFF_CNI   2917376u      // f32 [128]  char bi (n)
#define OFF_CNH   2917888u      // f32 [128]  char bh (n)
#define OFF_WRZ   2918400u      // f32 [1024] gru bi+bh (r,z)
#define OFF_WNI   2922496u      // f32 [512]  gru bi (n)
#define OFF_WNH   2924544u      // f32 [512]  gru bh (n)
#define OFF_CNT   2926592u      // 8 barrier counters, 256B apart (2KB)
#define OFF_FEATS 3145728u      // bf16 [32768][384]
#define OFF_XW    28311552u     // bf16 [32768][1536]
#define OFF_H     128974848u    // bf16 [32768][512]  (= [256][128][512])
#define WS_NEEDED 145752064ull

// ---------- K0: weight convert + bias fuse + counter zero ----------
__global__ void k_prep(const float* __restrict__ cWi, const float* __restrict__ cWh,
                       const float* __restrict__ gWi, const float* __restrict__ gWh,
                       const float* __restrict__ cemb,
                       const float* __restrict__ cbi, const float* __restrict__ cbh,
                       const float* __restrict__ gbi, const float* __restrict__ gbh,
                       uint16_t* o_cWi, uint16_t* o_cWh, uint16_t* o_gWi, uint16_t* o_gWh,
                       uint16_t* o_cemb, float* o_crz, float* o_cni, float* o_cnh,
                       float* o_wrz, float* o_wni, float* o_wnh, unsigned* cnt)
{
  int g = blockIdx.x * 256 + threadIdx.x;
  int st = gridDim.x * 256;
  for (int i = g; i < 24576;  i += st) o_cWi[i] = f2bf(cWi[i]);
  for (int i = g; i < 49152;  i += st) o_cWh[i] = f2bf(cWh[i]);
  for (int i = g; i < 589824; i += st) o_gWi[i] = f2bf(gWi[i]);
  for (int i = g; i < 786432; i += st) o_gWh[i] = f2bf(gWh[i]);
  for (int i = g; i < 8192;   i += st) o_cemb[i] = f2bf(cemb[i]);
  for (int i = g; i < 256;  i += st) o_crz[i] = cbi[i] + cbh[i];
  for (int i = g; i < 128;  i += st) { o_cni[i] = cbi[256 + i]; o_cnh[i] = cbh[256 + i]; }
  for (int i = g; i < 1024; i += st) o_wrz[i] = gbi[i] + gbh[i];
  for (int i = g; i < 512;  i += st) { o_wni[i] = gbi[1024 + i]; o_wnh[i] = gbh[1024 + i]; }
  for (int i = g; i < 512;  i += st) cnt[i] = 0u;   // 8 counters in 2KB region
}

// ---------- K2: word embedding gather -> feats[:, 0:256] ----------
__global__ void k_emb(const int* __restrict__ x, const float* __restrict__ embw,
                      uint16_t* __restrict__ feats)
{
  int n = blockIdx.x * 4 + (threadIdx.x >> 6);   // word row, n = t*128 + b
  int lane = threadIdx.x & 63;
  int t = n >> 7, b = n & 127;
  int wid = x[b * 256 + t];
  float4 v = *(const float4*)(embw + (size_t)wid * 256 + lane * 4);
  uint16_t* dst = feats + (size_t)n * 384 + lane * 4;
  dst[0] = f2bf(v.x); dst[1] = f2bf(v.y); dst[2] = f2bf(v.z); dst[3] = f2bf(v.w);
}

// ---------- K1: char GRU (batch-parallel, MFMA) -> feats[:, 256:384] ----------
// Grid 512 x 256 thr (4 waves, 16 words/wave). LDS: Wh[384][136] + ids[64][17] + h[64][136]
__global__ __launch_bounds__(256, 1) void k_char(
    const int* __restrict__ xch, const uint16_t* __restrict__ cembw,
    const uint16_t* __restrict__ cWi, const uint16_t* __restrict__ cWh,
    const float* __restrict__ crz, const float* __restrict__ cni,
    const float* __restrict__ cnh, uint16_t* __restrict__ feats)
{
  extern __shared__ char lds[];
  uint16_t* WhL = (uint16_t*)lds;                    // [384][136] bf16, 104448 B
  int*      idsL = (int*)(lds + 104448);             // [64][17], 4352 B
  uint16_t* hL  = (uint16_t*)(lds + 104448 + 4352);  // [64][136], 17408 B
  const int tid = threadIdx.x;
  const int wbase = blockIdx.x * 64;

  for (int i = tid; i < 384 * 16; i += 256) {
    int row = i >> 4, ch = i & 15;
    *(uint4*)(WhL + row * 136 + ch * 8) = *(const uint4*)(cWh + row * 128 + ch * 8);
  }
  for (int i = tid; i < 64 * 16; i += 256) {
    int w0 = i >> 4, p = i & 15;
    idsL[w0 * 17 + p] = xch[(wbase + w0) * 16 + p];
  }
  for (int i = tid; i < 64 * 136 / 2; i += 256) ((unsigned*)hL)[i] = 0u;
  __syncthreads();

  const int wv = tid >> 6, lane = tid & 63;
  const int q = lane >> 4, c = lane & 15;
  float br_[8], bz_[8], bni_[8], bnh_[8];
#pragma unroll
  for (int jb = 0; jb < 8; ++jb) {
    int j = jb * 16 + c;
    br_[jb] = crz[j]; bz_[jb] = crz[128 + j]; bni_[jb] = cni[j]; bnh_[jb] = cnh[j];
  }
  const int lwA = wv * 16 + c;        // word row for A-operand (m = lane&15)
  const int lwD = wv * 16 + q * 4;    // D rows base (+reg)

  for (int t = 0; t < 16; ++t) {
    f32x4 aRZ[16], aXN[8], aGN[8];
#pragma unroll
    for (int i = 0; i < 16; ++i) aRZ[i] = (f32x4)0.0f;
#pragma unroll
    for (int i = 0; i < 8; ++i) { aXN[i] = (f32x4)0.0f; aGN[i] = (f32x4)0.0f; }

    // xw contribution: cemb[word,t,:] @ Wi^T   (K=64)
    int id = idsL[lwA * 17 + t];
    const uint16_t* cerow = cembw + id * 64;
    short8 Ae0 = *(const short8*)(cerow + q * 8);
    short8 Ae1 = *(const short8*)(cerow + 32 + q * 8);
#pragma unroll
    for (int tl = 0; tl < 24; ++tl) {
      const uint16_t* wr = cWi + (tl * 16 + c) * 64 + q * 8;
      short8 B0 = *(const short8*)(wr);
      short8 B1 = *(const short8*)(wr + 32);
      if (tl < 16) { aRZ[tl] = MFMA16(Ae0, B0, aRZ[tl]); aRZ[tl] = MFMA16(Ae1, B1, aRZ[tl]); }
      else { aXN[tl - 16] = MFMA16(Ae0, B0, aXN[tl - 16]); aXN[tl - 16] = MFMA16(Ae1, B1, aXN[tl - 16]); }
    }
    // gh contribution: h @ Wh^T   (K=128); h=0 at t=0 is harmless
    short8 Ah[4];
#pragma unroll
    for (int kt = 0; kt < 4; ++kt) Ah[kt] = *(const short8*)(hL + lwA * 136 + kt * 32 + q * 8);
#pragma unroll
    for (int tl = 0; tl < 24; ++tl) {
#pragma unroll
      for (int kt = 0; kt < 4; ++kt) {
        short8 Bw = *(const short8*)(WhL + (tl * 16 + c) * 136 + kt * 32 + q * 8);
        if (tl < 16) aRZ[tl] = MFMA16(Ah[kt], Bw, aRZ[tl]);
        else aGN[tl - 16] = MFMA16(Ah[kt], Bw, aGN[tl - 16]);
      }
    }
    // gates + h update (f32)
#pragma unroll
    for (int jb = 0; jb < 8; ++jb) {
      int j = jb * 16 + c;
#pragma unroll
      for (int rg = 0; rg < 4; ++rg) {
        float r = fsig(aRZ[jb][rg] + br_[jb]);
        float z = fsig(aRZ[8 + jb][rg] + bz_[jb]);
        float n = ftanh_(aXN[jb][rg] + bni_[jb] + r * (aGN[jb][rg] + bnh_[jb]));
        int hoff = (lwD + rg) * 136 + j;
        float hold = bf2f(hL[hoff]);
        hL[hoff] = f2bf((1.0f - z) * n + z * hold);
      }
    }
  }
  __syncthreads();
  for (int i = tid; i < 64 * 128; i += 256) {
    int w0 = i >> 7, col = i & 127;
    feats[(size_t)(wbase + w0) * 384 + 256 + col] = hL[w0 * 136 + col];
  }
}

// ---------- K3: xw = feats @ gru_Wi^T  (M=32768, N=1536, K=384) ----------
__global__ __launch_bounds__(256) void k_gemm_xw(
    const uint16_t* __restrict__ A, const uint16_t* __restrict__ Bm,
    uint16_t* __restrict__ C)
{
  __shared__ uint16_t AL[128 * 40];
  __shared__ uint16_t BL[128 * 40];
  const int tid = threadIdx.x;
  const int bm = blockIdx.x & 255, bn = blockIdx.x >> 8;
  const int m0 = bm * 128, n0 = bn * 128;
  const int wv = tid >> 6, lane = tid & 63, q = lane >> 4, c = lane & 15;
  const int vm = (wv >> 1) * 64, vn = (wv & 1) * 64;
  f32x4 acc[4][4];
#pragma unroll
  for (int mt = 0; mt < 4; ++mt)
#pragma unroll
    for (int nt = 0; nt < 4; ++nt) acc[mt][nt] = (f32x4)0.0f;

  for (int k0 = 0; k0 < 384; k0 += 32) {
    __syncthreads();
    for (int i2 = tid; i2 < 512; i2 += 256) {
      int row = i2 >> 2, cc = i2 & 3;
      *(uint4*)(AL + row * 40 + cc * 8) = *(const uint4*)(A + (size_t)(m0 + row) * 384 + k0 + cc * 8);
      *(uint4*)(BL + row * 40 + cc * 8) = *(const uint4*)(Bm + (size_t)(n0 + row) * 384 + k0 + cc * 8);
    }
    __syncthreads();
    short8 af[4], bfr[4];
#pragma unroll
    for (int mt = 0; mt < 4; ++mt) af[mt] = *(const short8*)(AL + (vm + mt * 16 + c) * 40 + q * 8);
#pragma unroll
    for (int nt = 0; nt < 4; ++nt) bfr[nt] = *(const short8*)(BL + (vn + nt * 16 + c) * 40 + q * 8);
#pragma unroll
    for (int mt = 0; mt < 4; ++mt)
#pragma unroll
      for (int nt = 0; nt < 4; ++nt) acc[mt][nt] = MFMA16(af[mt], bfr[nt], acc[mt][nt]);
  }
#pragma unroll
  for (int mt = 0; mt < 4; ++mt)
#pragma unroll
    for (int nt = 0; nt < 4; ++nt)
#pragma unroll
      for (int rg = 0; rg < 4; ++rg) {
        int m = m0 + vm + mt * 16 + q * 4 + rg;
        int n = n0 + vn + nt * 16 + c;
        C[(size_t)m * 1536 + n] = f2bf(acc[mt][nt][rg]);
      }
}

// ---------- K4: word GRU, persistent, 128 WGs x 64 thr ----------
// WG (gb,gc): batches [gb*16, +16), hidden cols [gc*32, +32). LDS Wh slice [96][520] bf16.
// Barrier: per-batch-group (16 WGs share counter cnt[gb*64]); ONE atomic per WG.
__global__ __launch_bounds__(64, 1) void k_gru(
    const uint16_t* __restrict__ xw, const uint16_t* __restrict__ gWh,
    const float* __restrict__ wrz, const float* __restrict__ wni,
    const float* __restrict__ wnh, uint16_t* __restrict__ H,
    unsigned* __restrict__ cnt)
{
  extern __shared__ char lds[];
  uint16_t* WhL = (uint16_t*)lds;   // [96][520] = 99840 B
  const int tid = threadIdx.x;
  const int gb = blockIdx.x >> 4, gc = blockIdx.x & 15;
  const int m0 = gb * 16, j0 = gc * 32;
  unsigned* myCnt = cnt + (gb << 6);   // 8 counters, 256B apart
  for (int i = tid; i < 96 * 64; i += 64) {
    int row = i >> 6, ch = i & 63;
    int gr = (row < 32) ? (j0 + row) : (row < 64) ? (512 + j0 + row - 32) : (1024 + j0 + row - 64);
    *(uint4*)(WhL + row * 520 + ch * 8) = *(const uint4*)(gWh + (size_t)gr * 512 + ch * 8);
  }
  const int q = tid >> 4, c = tid & 15;
  const int j1 = j0 + c, j2 = j0 + 16 + c;
  const float br0 = wrz[j1], br1 = wrz[j2];
  const float bz0 = wrz[512 + j1], bz1 = wrz[512 + j2];
  const float bi0 = wni[j1], bi1 = wni[j2];
  const float bh0 = wnh[j1], bh1 = wnh[j2];
  __syncthreads();

  for (int t = 0; t < 256; ++t) {
    const uint16_t* xwt = xw + (size_t)(t * 128 + m0) * 1536;
    f32x4 acc[6];
#pragma unroll
    for (int rg = 0; rg < 4; ++rg) {
      const uint16_t* rowp = xwt + (q * 4 + rg) * 1536;
      acc[0][rg] = bf2f(rowp[j1]);
      acc[1][rg] = bf2f(rowp[j2]);
      acc[2][rg] = bf2f(rowp[512 + j1]);
      acc[3][rg] = bf2f(rowp[512 + j2]);
      acc[4][rg] = 0.0f; acc[5][rg] = 0.0f;
    }
    if (t > 0) {
      const uint16_t* hp = H + (size_t)((t - 1) * 128 + m0) * 512 + c * 512;
#pragma unroll 4
      for (int kt = 0; kt < 16; ++kt) {
        short8 a = *(const short8*)(hp + kt * 32 + q * 8);
#pragma unroll
        for (int tl = 0; tl < 6; ++tl) {
          short8 b = *(const short8*)(WhL + (tl * 16 + c) * 520 + kt * 32 + q * 8);
          acc[tl] = MFMA16(a, b, acc[tl]);
        }
      }
    }
    const uint16_t* hprev = H + (size_t)(((t > 0 ? t : 1) - 1) * 128 + m0) * 512;
    uint16_t* hcur = H + (size_t)(t * 128 + m0) * 512;
#pragma unroll
    for (int rg = 0; rg < 4; ++rg) {
      int m = q * 4 + rg;
      const uint16_t* xr = xwt + m * 1536;
      float r0 = fsig(acc[0][rg] + br0);
      float z0 = fsig(acc[2][rg] + bz0);
      float n0 = ftanh_(bf2f(xr[1024 + j1]) + bi0 + r0 * (acc[4][rg] + bh0));
      float h0 = (t > 0) ? bf2f(hprev[m * 512 + j1]) : 0.0f;
      hcur[m * 512 + j1] = f2bf((1.0f - z0) * n0 + z0 * h0);
      float r1 = fsig(acc[1][rg] + br1);
      float z1 = fsig(acc[3][rg] + bz1);
      float n1 = ftanh_(bf2f(xr[1024 + j2]) + bi1 + r1 * (acc[5][rg] + bh1));
      float h1 = (t > 0) ? bf2f(hprev[m * 512 + j2]) : 0.0f;
      hcur[m * 512 + j2] = f2bf((1.0f - z1) * n1 + z1 * h1);
    }
    if (t == 255) break;   // no barrier after final step
    // ---- group barrier: flush, ONE atomic arrive per WG, wave spins on load ----
    __threadfence();
    if (tid == 0) __hip_atomic_fetch_add(myCnt, 1u, __ATOMIC_RELAXED, __HIP_MEMORY_SCOPE_AGENT);
    const unsigned target = (unsigned)(t + 1) * 16u;  // 16 WGs per batch group
    int spins = 0;
    while (__hip_atomic_load(myCnt, __ATOMIC_RELAXED, __HIP_MEMORY_SCOPE_AGENT) < target) {
      __builtin_amdgcn_s_sleep(1);
      if (++spins > 2000000) break;   // safety: wrong-but-terminating beats deadlock
    }
    __threadfence();
  }
}

// ---------- K5: classifier pred[b,t,c] = H[t,b,:] . cls_W[c,:] + cls_b[c] ----------
__global__ void k_cls(const uint16_t* __restrict__ H, const float* __restrict__ W,
                      const float* __restrict__ bb, float* __restrict__ out)
{
  int g = blockIdx.x * 256 + threadIdx.x;   // 655360 = 32768 rows * 20
  int c = g % 20, row = g / 20;
  int t = row >> 7, b = row & 127;
  const uint16_t* hp = H + (size_t)row * 512;
  const float* wp = W + c * 512;
  float acc = 0.0f;
  for (int i = 0; i < 512; i += 8) {
    uint4 hv = *(const uint4*)(hp + i);
    float4 w0 = *(const float4*)(wp + i);
    float4 w1 = *(const float4*)(wp + i + 4);
    acc += bf2f((uint16_t)hv.x) * w0.x + bf2f((uint16_t)(hv.x >> 16)) * w0.y
         + bf2f((uint16_t)hv.y) * w0.z + bf2f((uint16_t)(hv.y >> 16)) * w0.w
         + bf2f((uint16_t)hv.z) * w1.x + bf2f((uint16_t)(hv.z >> 16)) * w1.y
         + bf2f((uint16_t)hv.w) * w1.z + bf2f((uint16_t)(hv.w >> 16)) * w1.w;
  }
  out[((size_t)b * 256 + t) * 20 + c] = acc + bb[c];
}

// ---------- launch ----------
extern "C" void kernel_launch(void* const* d_in, const int* in_sizes, int n_in,
                              void* d_out, int out_size, void* d_ws, size_t ws_size,
                              hipStream_t stream) {
  (void)in_sizes; (void)n_in; (void)out_size;
  const int*   x     = (const int*)d_in[0];
  const int*   xch   = (const int*)d_in[1];
  const float* embw  = (const float*)d_in[2];
  const float* cembw = (const float*)d_in[3];
  const float* cWi   = (const float*)d_in[4];
  const float* cWh   = (const float*)d_in[5];
  const float* cbi   = (const float*)d_in[6];
  const float* cbh   = (const float*)d_in[7];
  const float* gWi   = (const float*)d_in[8];
  const float* gWh   = (const float*)d_in[9];
  const float* gbi   = (const float*)d_in[10];
  const float* gbh   = (const float*)d_in[11];
  const float* clsW  = (const float*)d_in[12];
  const float* clsb  = (const float*)d_in[13];
  float* out = (float*)d_out;
  char* w = (char*)d_ws;

  if (ws_size < WS_NEEDED) { fprintf(stderr, "ws too small: %zu < %llu\n", ws_size, WS_NEEDED); return; }

  uint16_t* o_cWi  = (uint16_t*)(w + OFF_CWI);
  uint16_t* o_cWh  = (uint16_t*)(w + OFF_CWH);
  uint16_t* o_gWi  = (uint16_t*)(w + OFF_GWI);
  uint16_t* o_gWh  = (uint16_t*)(w + OFF_GWH);
  uint16_t* o_cemb = (uint16_t*)(w + OFF_CEMB);
  float* crz = (float*)(w + OFF_CRZ);
  float* cni = (float*)(w + OFF_CNI);
  float* cnh = (float*)(w + OFF_CNH);
  float* wrz = (float*)(w + OFF_WRZ);
  float* wni = (float*)(w + OFF_WNI);
  float* wnh = (float*)(w + OFF_WNH);
  unsigned* cnt = (unsigned*)(w + OFF_CNT);
  uint16_t* feats = (uint16_t*)(w + OFF_FEATS);
  uint16_t* xwb   = (uint16_t*)(w + OFF_XW);
  uint16_t* Hb    = (uint16_t*)(w + OFF_H);

  // >64KB dynamic LDS kernels need the attribute; idempotent, host-side only.
  (void)hipFuncSetAttribute((const void*)k_char, hipFuncAttributeMaxDynamicSharedMemorySize, 126208);
  (void)hipFuncSetAttribute((const void*)k_gru,  hipFuncAttributeMaxDynamicSharedMemorySize, 99840);

  k_prep<<<512, 256, 0, stream>>>(cWi, cWh, gWi, gWh, cembw, cbi, cbh, gbi, gbh,
                                  o_cWi, o_cWh, o_gWi, o_gWh, o_cemb,
                                  crz, cni, cnh, wrz, wni, wnh, cnt);
  k_emb<<<8192, 256, 0, stream>>>(x, embw, feats);
  k_char<<<512, 256, 126208, stream>>>(xch, o_cemb, o_cWi, o_cWh, crz, cni, cnh, feats);
  k_gemm_xw<<<3072, 256, 0, stream>>>(feats, o_gWi, xwb);
  k_gru<<<128, 64, 99840, stream>>>(xwb, o_gWh, wrz, wni, wnh, Hb, cnt);
  k_cls<<<2560, 256, 0, stream>>>(Hb, clsW, clsb, out);
}

// Round 3
// 2761.103 us; speedup vs baseline: 1.6086x; 1.2371x over previous
//
#include <hip/hip_runtime.h>
#include <cstdio>
#include <cstdint>

// ---------- types / helpers ----------
typedef __attribute__((ext_vector_type(8))) short short8;   // 8 bf16 (4 VGPRs)
typedef __attribute__((ext_vector_type(4))) float f32x4;    // MFMA 16x16 acc

__device__ __forceinline__ f32x4 MFMA16(short8 a, short8 b, f32x4 c) {
  return __builtin_amdgcn_mfma_f32_16x16x32_bf16(a, b, c, 0, 0, 0);
}
__device__ __forceinline__ float bf2f(uint16_t u) {
  union { uint32_t u; float f; } v; v.u = ((uint32_t)u) << 16; return v.f;
}
__device__ __forceinline__ uint16_t f2bf(float f) {
  union { float f; uint32_t u; } v; v.f = f;
  uint32_t r = v.u + 0x7fffu + ((v.u >> 16) & 1u);  // RNE
  return (uint16_t)(r >> 16);
}
__device__ __forceinline__ float fsig(float x) { return 1.0f / (1.0f + __expf(-x)); }
__device__ __forceinline__ float ftanh_(float x) { return 2.0f / (1.0f + __expf(-2.0f * x)) - 1.0f; }

// Problem dims
// B=128 S=256 L=16, EMB=256 HID=512, CEMB=64 CHID=128, NCLS=20
// word rows n = t*128 + b  (matches x_chars.reshape(S*B, L))

// ---------- ws layout (bytes) ----------
#define OFF_CWI   0u            // char_Wi bf16 [384][64]
#define OFF_CWH   49152u        // char_Wh bf16 [384][128]
#define OFF_GWI   147456u       // gru_Wi  bf16 [1536][384]
#define OFF_GWH   1327104u      // gru_Wh  bf16 [1536][512]
#define OFF_CEMB  2899968u      // char_emb bf16 [128][64]
#define OFF_CRZ   2916352u      // f32 [256]  char bi+bh (r,z)
#define OFF_CNI   2917376u      // f32 [128]  char bi (n)
#define OFF_CNH   2917888u      // f32 [128]  char bh (n)
#define OFF_WRZ   2918400u      // f32 [1024] gru bi+bh (r,z)
#define OFF_WNI   2922496u      // f32 [512]  gru bi (n)
#define OFF_WNH   2924544u      // f32 [512]  gru bh (n)
#define OFF_CNT   2926592u      // 4KB counter region (1024 uints):
                                //   [gb*64]      step barrier counters (8, 256B apart)
                                //   [512]        topology rendezvous counter
                                //   [896+x]      per-XCD claim counters (8)
#define OFF_FEATS 3145728u      // bf16 [32768][384]
#define OFF_XW    28311552u     // bf16 [32768][1536]
#define OFF_H     128974848u    // bf16 [32768][512]  (= [256][128][512])
#define WS_NEEDED 145752064ull

// ---------- K0: weight convert + bias fuse + counter zero ----------
__global__ void k_prep(const float* __restrict__ cWi, const float* __restrict__ cWh,
                       const float* __restrict__ gWi, const float* __restrict__ gWh,
                       const float* __restrict__ cemb,
                       const float* __restrict__ cbi, const float* __restrict__ cbh,
                       const float* __restrict__ gbi, const float* __restrict__ gbh,
                       uint16_t* o_cWi, uint16_t* o_cWh, uint16_t* o_gWi, uint16_t* o_gWh,
                       uint16_t* o_cemb, float* o_crz, float* o_cni, float* o_cnh,
                       float* o_wrz, float* o_wni, float* o_wnh, unsigned* cnt)
{
  int g = blockIdx.x * 256 + threadIdx.x;
  int st = gridDim.x * 256;
  for (int i = g; i < 24576;  i += st) o_cWi[i] = f2bf(cWi[i]);
  for (int i = g; i < 49152;  i += st) o_cWh[i] = f2bf(cWh[i]);
  for (int i = g; i < 589824; i += st) o_gWi[i] = f2bf(gWi[i]);
  for (int i = g; i < 786432; i += st) o_gWh[i] = f2bf(gWh[i]);
  for (int i = g; i < 8192;   i += st) o_cemb[i] = f2bf(cemb[i]);
  for (int i = g; i < 256;  i += st) o_crz[i] = cbi[i] + cbh[i];
  for (int i = g; i < 128;  i += st) { o_cni[i] = cbi[256 + i]; o_cnh[i] = cbh[256 + i]; }
  for (int i = g; i < 1024; i += st) o_wrz[i] = gbi[i] + gbh[i];
  for (int i = g; i < 512;  i += st) { o_wni[i] = gbi[1024 + i]; o_wnh[i] = gbh[1024 + i]; }
  for (int i = g; i < 1024; i += st) cnt[i] = 0u;   // whole 4KB counter region
}

// ---------- K2: word embedding gather -> feats[:, 0:256] ----------
__global__ void k_emb(const int* __restrict__ x, const float* __restrict__ embw,
                      uint16_t* __restrict__ feats)
{
  int n = blockIdx.x * 4 + (threadIdx.x >> 6);   // word row, n = t*128 + b
  int lane = threadIdx.x & 63;
  int t = n >> 7, b = n & 127;
  int wid = x[b * 256 + t];
  float4 v = *(const float4*)(embw + (size_t)wid * 256 + lane * 4);
  uint16_t* dst = feats + (size_t)n * 384 + lane * 4;
  dst[0] = f2bf(v.x); dst[1] = f2bf(v.y); dst[2] = f2bf(v.z); dst[3] = f2bf(v.w);
}

// ---------- K1: char GRU (batch-parallel, MFMA) -> feats[:, 256:384] ----------
// Grid 512 x 256 thr (4 waves, 16 words/wave). LDS: Wh[384][136] + ids[64][17] + h[64][136]
__global__ __launch_bounds__(256, 1) void k_char(
    const int* __restrict__ xch, const uint16_t* __restrict__ cembw,
    const uint16_t* __restrict__ cWi, const uint16_t* __restrict__ cWh,
    const float* __restrict__ crz, const float* __restrict__ cni,
    const float* __restrict__ cnh, uint16_t* __restrict__ feats)
{
  extern __shared__ char lds[];
  uint16_t* WhL = (uint16_t*)lds;                    // [384][136] bf16, 104448 B
  int*      idsL = (int*)(lds + 104448);             // [64][17], 4352 B
  uint16_t* hL  = (uint16_t*)(lds + 104448 + 4352);  // [64][136], 17408 B
  const int tid = threadIdx.x;
  const int wbase = blockIdx.x * 64;

  for (int i = tid; i < 384 * 16; i += 256) {
    int row = i >> 4, ch = i & 15;
    *(uint4*)(WhL + row * 136 + ch * 8) = *(const uint4*)(cWh + row * 128 + ch * 8);
  }
  for (int i = tid; i < 64 * 16; i += 256) {
    int w0 = i >> 4, p = i & 15;
    idsL[w0 * 17 + p] = xch[(wbase + w0) * 16 + p];
  }
  for (int i = tid; i < 64 * 136 / 2; i += 256) ((unsigned*)hL)[i] = 0u;
  __syncthreads();

  const int wv = tid >> 6, lane = tid & 63;
  const int q = lane >> 4, c = lane & 15;
  float br_[8], bz_[8], bni_[8], bnh_[8];
#pragma unroll
  for (int jb = 0; jb < 8; ++jb) {
    int j = jb * 16 + c;
    br_[jb] = crz[j]; bz_[jb] = crz[128 + j]; bni_[jb] = cni[j]; bnh_[jb] = cnh[j];
  }
  const int lwA = wv * 16 + c;        // word row for A-operand (m = lane&15)
  const int lwD = wv * 16 + q * 4;    // D rows base (+reg)

  for (int t = 0; t < 16; ++t) {
    f32x4 aRZ[16], aXN[8], aGN[8];
#pragma unroll
    for (int i = 0; i < 16; ++i) aRZ[i] = (f32x4)0.0f;
#pragma unroll
    for (int i = 0; i < 8; ++i) { aXN[i] = (f32x4)0.0f; aGN[i] = (f32x4)0.0f; }

    // xw contribution: cemb[word,t,:] @ Wi^T   (K=64)
    int id = idsL[lwA * 17 + t];
    const uint16_t* cerow = cembw + id * 64;
    short8 Ae0 = *(const short8*)(cerow + q * 8);
    short8 Ae1 = *(const short8*)(cerow + 32 + q * 8);
#pragma unroll
    for (int tl = 0; tl < 24; ++tl) {
      const uint16_t* wr = cWi + (tl * 16 + c) * 64 + q * 8;
      short8 B0 = *(const short8*)(wr);
      short8 B1 = *(const short8*)(wr + 32);
      if (tl < 16) { aRZ[tl] = MFMA16(Ae0, B0, aRZ[tl]); aRZ[tl] = MFMA16(Ae1, B1, aRZ[tl]); }
      else { aXN[tl - 16] = MFMA16(Ae0, B0, aXN[tl - 16]); aXN[tl - 16] = MFMA16(Ae1, B1, aXN[tl - 16]); }
    }
    // gh contribution: h @ Wh^T   (K=128); h=0 at t=0 is harmless
    short8 Ah[4];
#pragma unroll
    for (int kt = 0; kt < 4; ++kt) Ah[kt] = *(const short8*)(hL + lwA * 136 + kt * 32 + q * 8);
#pragma unroll
    for (int tl = 0; tl < 24; ++tl) {
#pragma unroll
      for (int kt = 0; kt < 4; ++kt) {
        short8 Bw = *(const short8*)(WhL + (tl * 16 + c) * 136 + kt * 32 + q * 8);
        if (tl < 16) aRZ[tl] = MFMA16(Ah[kt], Bw, aRZ[tl]);
        else aGN[tl - 16] = MFMA16(Ah[kt], Bw, aGN[tl - 16]);
      }
    }
    // gates + h update (f32)
#pragma unroll
    for (int jb = 0; jb < 8; ++jb) {
      int j = jb * 16 + c;
#pragma unroll
      for (int rg = 0; rg < 4; ++rg) {
        float r = fsig(aRZ[jb][rg] + br_[jb]);
        float z = fsig(aRZ[8 + jb][rg] + bz_[jb]);
        float n = ftanh_(aXN[jb][rg] + bni_[jb] + r * (aGN[jb][rg] + bnh_[jb]));
        int hoff = (lwD + rg) * 136 + j;
        float hold = bf2f(hL[hoff]);
        hL[hoff] = f2bf((1.0f - z) * n + z * hold);
      }
    }
  }
  __syncthreads();
  for (int i = tid; i < 64 * 128; i += 256) {
    int w0 = i >> 7, col = i & 127;
    feats[(size_t)(wbase + w0) * 384 + 256 + col] = hL[w0 * 136 + col];
  }
}

// ---------- K3: xw = feats @ gru_Wi^T  (M=32768, N=1536, K=384) ----------
__global__ __launch_bounds__(256) void k_gemm_xw(
    const uint16_t* __restrict__ A, const uint16_t* __restrict__ Bm,
    uint16_t* __restrict__ C)
{
  __shared__ uint16_t AL[128 * 40];
  __shared__ uint16_t BL[128 * 40];
  const int tid = threadIdx.x;
  const int bm = blockIdx.x & 255, bn = blockIdx.x >> 8;
  const int m0 = bm * 128, n0 = bn * 128;
  const int wv = tid >> 6, lane = tid & 63, q = lane >> 4, c = lane & 15;
  const int vm = (wv >> 1) * 64, vn = (wv & 1) * 64;
  f32x4 acc[4][4];
#pragma unroll
  for (int mt = 0; mt < 4; ++mt)
#pragma unroll
    for (int nt = 0; nt < 4; ++nt) acc[mt][nt] = (f32x4)0.0f;

  for (int k0 = 0; k0 < 384; k0 += 32) {
    __syncthreads();
    for (int i2 = tid; i2 < 512; i2 += 256) {
      int row = i2 >> 2, cc = i2 & 3;
      *(uint4*)(AL + row * 40 + cc * 8) = *(const uint4*)(A + (size_t)(m0 + row) * 384 + k0 + cc * 8);
      *(uint4*)(BL + row * 40 + cc * 8) = *(const uint4*)(Bm + (size_t)(n0 + row) * 384 + k0 + cc * 8);
    }
    __syncthreads();
    short8 af[4], bfr[4];
#pragma unroll
    for (int mt = 0; mt < 4; ++mt) af[mt] = *(const short8*)(AL + (vm + mt * 16 + c) * 40 + q * 8);
#pragma unroll
    for (int nt = 0; nt < 4; ++nt) bfr[nt] = *(const short8*)(BL + (vn + nt * 16 + c) * 40 + q * 8);
#pragma unroll
    for (int mt = 0; mt < 4; ++mt)
#pragma unroll
      for (int nt = 0; nt < 4; ++nt) acc[mt][nt] = MFMA16(af[mt], bfr[nt], acc[mt][nt]);
  }
#pragma unroll
  for (int mt = 0; mt < 4; ++mt)
#pragma unroll
    for (int nt = 0; nt < 4; ++nt)
#pragma unroll
      for (int rg = 0; rg < 4; ++rg) {
        int m = m0 + vm + mt * 16 + q * 4 + rg;
        int n = n0 + vn + nt * 16 + c;
        C[(size_t)m * 1536 + n] = f2bf(acc[mt][nt][rg]);
      }
}

// ---------- K4: word GRU, persistent, 128 WGs x 64 thr ----------
// Runtime topology discovery: groups of 16 WGs formed WITHIN one XCD when the
// block->XCD placement allows it (per-XCD WG counts all multiples of 16).
// Fast path: H exchange via XCD-local L2 (plain ld/st + vmcnt), L3 atomics for
// the barrier counter, NO L2 flush/invalidate. Fallback: device-scope fences.
__global__ __launch_bounds__(64, 1) void k_gru(
    const uint16_t* __restrict__ xw, const uint16_t* __restrict__ gWh,
    const float* __restrict__ wrz, const float* __restrict__ wni,
    const float* __restrict__ wnh, uint16_t* __restrict__ H,
    unsigned* __restrict__ cnt)
{
  extern __shared__ char lds[];
  uint16_t* WhL = (uint16_t*)lds;   // [96][520] = 99840 B
  const int tid = threadIdx.x;

  // ---- Phase A: topology discovery (one rendezvous of all 128 WGs) ----
  unsigned xcd;
  asm volatile("s_getreg_b32 %0, hwreg(HW_REG_XCC_ID, 0, 4)" : "=s"(xcd));
  unsigned* xcnt = cnt + 896;   // per-XCD claim counters
  unsigned* rdv  = cnt + 512;   // rendezvous counter
  int myslot = 0;
  if (tid == 0) {
    myslot = (int)__hip_atomic_fetch_add(&xcnt[xcd], 1u, __ATOMIC_RELAXED, __HIP_MEMORY_SCOPE_AGENT);
    __hip_atomic_fetch_add(rdv, 1u, __ATOMIC_RELEASE, __HIP_MEMORY_SCOPE_AGENT);
  }
  myslot = __shfl(myslot, 0);
  {
    int sp = 0;
    while (__hip_atomic_load(rdv, __ATOMIC_ACQUIRE, __HIP_MEMORY_SCOPE_AGENT) < 128u) {
      __builtin_amdgcn_s_sleep(1);
      if (++sp > 10000000) break;
    }
  }
  unsigned G = 0, base = 0;
#pragma unroll
  for (int x2 = 0; x2 < 8; ++x2) {
    unsigned v = __hip_atomic_load(&xcnt[x2], __ATOMIC_RELAXED, __HIP_MEMORY_SCOPE_AGENT) >> 4;
    if ((unsigned)x2 < xcd) base += v;
    G += v;
  }
  bool fastp; int gb, gc;
  if (G == 8u) { fastp = true; gb = (int)(base + ((unsigned)myslot >> 4)); gc = myslot & 15; }
  else         { fastp = false; gb = blockIdx.x & 7; gc = blockIdx.x >> 3; }

  const int m0 = gb * 16, j0 = gc * 32;
  unsigned* myCnt = cnt + (gb << 6);   // step barrier counters, 256B apart

  for (int i = tid; i < 96 * 64; i += 64) {
    int row = i >> 6, ch = i & 63;
    int gr = (row < 32) ? (j0 + row) : (row < 64) ? (512 + j0 + row - 32) : (1024 + j0 + row - 64);
    *(uint4*)(WhL + row * 520 + ch * 8) = *(const uint4*)(gWh + (size_t)gr * 512 + ch * 8);
  }
  const int q = tid >> 4, c = tid & 15;
  const int j1 = j0 + c, j2 = j0 + 16 + c;
  const float br0 = wrz[j1], br1 = wrz[j2];
  const float bz0 = wrz[512 + j1], bz1 = wrz[512 + j2];
  const float bi0 = wni[j1], bi1 = wni[j2];
  const float bh0 = wnh[j1], bh1 = wnh[j2];
  __syncthreads();

  // xw register prefetch for step 0; h_old kept in registers
  uint16_t pf[4][6];
  {
    const uint16_t* xwt = xw + (size_t)m0 * 1536;
#pragma unroll
    for (int rg = 0; rg < 4; ++rg) {
      const uint16_t* rowp = xwt + (q * 4 + rg) * 1536;
      pf[rg][0] = rowp[j1];        pf[rg][1] = rowp[j2];
      pf[rg][2] = rowp[512 + j1];  pf[rg][3] = rowp[512 + j2];
      pf[rg][4] = rowp[1024 + j1]; pf[rg][5] = rowp[1024 + j2];
    }
  }
  float hold1[4] = {0.f, 0.f, 0.f, 0.f}, hold2[4] = {0.f, 0.f, 0.f, 0.f};

  for (int t = 0; t < 256; ++t) {
    f32x4 acc[6];
    float xn1[4], xn2[4];
#pragma unroll
    for (int rg = 0; rg < 4; ++rg) {
      acc[0][rg] = bf2f(pf[rg][0]); acc[1][rg] = bf2f(pf[rg][1]);
      acc[2][rg] = bf2f(pf[rg][2]); acc[3][rg] = bf2f(pf[rg][3]);
      acc[4][rg] = 0.0f; acc[5][rg] = 0.0f;
      xn1[rg] = bf2f(pf[rg][4]); xn2[rg] = bf2f(pf[rg][5]);
    }
    // prefetch xw for t+1 (overlaps MFMA + barrier of this step)
    if (t < 255) {
      const uint16_t* xwn = xw + (size_t)((t + 1) * 128 + m0) * 1536;
#pragma unroll
      for (int rg = 0; rg < 4; ++rg) {
        const uint16_t* rowp = xwn + (q * 4 + rg) * 1536;
        pf[rg][0] = rowp[j1];        pf[rg][1] = rowp[j2];
        pf[rg][2] = rowp[512 + j1];  pf[rg][3] = rowp[512 + j2];
        pf[rg][4] = rowp[1024 + j1]; pf[rg][5] = rowp[1024 + j2];
      }
    }
    if (t > 0) {
      const uint16_t* hp = H + (size_t)((t - 1) * 128 + m0) * 512 + c * 512;
#pragma unroll 4
      for (int kt = 0; kt < 16; ++kt) {
        short8 a = *(const short8*)(hp + kt * 32 + q * 8);
#pragma unroll
        for (int tl = 0; tl < 6; ++tl) {
          short8 b = *(const short8*)(WhL + (tl * 16 + c) * 520 + kt * 32 + q * 8);
          acc[tl] = MFMA16(a, b, acc[tl]);
        }
      }
    }
    uint16_t* hcur = H + (size_t)(t * 128 + m0) * 512;
#pragma unroll
    for (int rg = 0; rg < 4; ++rg) {
      int m = q * 4 + rg;
      float r0 = fsig(acc[0][rg] + br0);
      float z0 = fsig(acc[2][rg] + bz0);
      float n0 = ftanh_(xn1[rg] + bi0 + r0 * (acc[4][rg] + bh0));
      float h0 = (1.0f - z0) * n0 + z0 * hold1[rg];
      hold1[rg] = h0;
      hcur[m * 512 + j1] = f2bf(h0);
      float r1 = fsig(acc[1][rg] + br1);
      float z1 = fsig(acc[3][rg] + bz1);
      float n1 = ftanh_(xn2[rg] + bi1 + r1 * (acc[5][rg] + bh1));
      float h1 = (1.0f - z1) * n1 + z1 * hold2[rg];
      hold2[rg] = h1;
      hcur[m * 512 + j2] = f2bf(h1);
    }
    if (t == 255) break;   // no barrier after final step
    const unsigned target = (unsigned)(t + 1) * 16u;  // 16 WGs per batch group
    if (fastp) {
      // release to XCD-local L2: just drain VM ops; no L2 flush
      asm volatile("s_waitcnt vmcnt(0)" ::: "memory");
      if (tid == 0) __hip_atomic_fetch_add(myCnt, 1u, __ATOMIC_RELAXED, __HIP_MEMORY_SCOPE_AGENT);
      int sp = 0;
      while (__hip_atomic_load(myCnt, __ATOMIC_RELAXED, __HIP_MEMORY_SCOPE_AGENT) < target) {
        if (++sp > 4000000) break;   // safety
      }
      asm volatile("" ::: "memory");
    } else {
      __threadfence();
      if (tid == 0) __hip_atomic_fetch_add(myCnt, 1u, __ATOMIC_RELAXED, __HIP_MEMORY_SCOPE_AGENT);
      int sp = 0;
      while (__hip_atomic_load(myCnt, __ATOMIC_RELAXED, __HIP_MEMORY_SCOPE_AGENT) < target) {
        __builtin_amdgcn_s_sleep(1);
        if (++sp > 2000000) break;   // safety
      }
      __threadfence();
    }
  }
}

// ---------- K5: classifier pred[b,t,c] = H[t,b,:] . cls_W[c,:] + cls_b[c] ----------
__global__ void k_cls(const uint16_t* __restrict__ H, const float* __restrict__ W,
                      const float* __restrict__ bb, float* __restrict__ out)
{
  int g = blockIdx.x * 256 + threadIdx.x;   // 655360 = 32768 rows * 20
  int c = g % 20, row = g / 20;
  int t = row >> 7, b = row & 127;
  const uint16_t* hp = H + (size_t)row * 512;
  const float* wp = W + c * 512;
  float acc = 0.0f;
  for (int i = 0; i < 512; i += 8) {
    uint4 hv = *(const uint4*)(hp + i);
    float4 w0 = *(const float4*)(wp + i);
    float4 w1 = *(const float4*)(wp + i + 4);
    acc += bf2f((uint16_t)hv.x) * w0.x + bf2f((uint16_t)(hv.x >> 16)) * w0.y
         + bf2f((uint16_t)hv.y) * w0.z + bf2f((uint16_t)(hv.y >> 16)) * w0.w
         + bf2f((uint16_t)hv.z) * w1.x + bf2f((uint16_t)(hv.z >> 16)) * w1.y
         + bf2f((uint16_t)hv.w) * w1.z + bf2f((uint16_t)(hv.w >> 16)) * w1.w;
  }
  out[((size_t)b * 256 + t) * 20 + c] = acc + bb[c];
}

// ---------- launch ----------
extern "C" void kernel_launch(void* const* d_in, const int* in_sizes, int n_in,
                              void* d_out, int out_size, void* d_ws, size_t ws_size,
                              hipStream_t stream) {
  (void)in_sizes; (void)n_in; (void)out_size;
  const int*   x     = (const int*)d_in[0];
  const int*   xch   = (const int*)d_in[1];
  const float* embw  = (const float*)d_in[2];
  const float* cembw = (const float*)d_in[3];
  const float* cWi   = (const float*)d_in[4];
  const float* cWh   = (const float*)d_in[5];
  const float* cbi   = (const float*)d_in[6];
  const float* cbh   = (const float*)d_in[7];
  const float* gWi   = (const float*)d_in[8];
  const float* gWh   = (const float*)d_in[9];
  const float* gbi   = (const float*)d_in[10];
  const float* gbh   = (const float*)d_in[11];
  const float* clsW  = (const float*)d_in[12];
  const float* clsb  = (const float*)d_in[13];
  float* out = (float*)d_out;
  char* w = (char*)d_ws;

  if (ws_size < WS_NEEDED) { fprintf(stderr, "ws too small: %zu < %llu\n", ws_size, WS_NEEDED); return; }

  uint16_t* o_cWi  = (uint16_t*)(w + OFF_CWI);
  uint16_t* o_cWh  = (uint16_t*)(w + OFF_CWH);
  uint16_t* o_gWi  = (uint16_t*)(w + OFF_GWI);
  uint16_t* o_gWh  = (uint16_t*)(w + OFF_GWH);
  uint16_t* o_cemb = (uint16_t*)(w + OFF_CEMB);
  float* crz = (float*)(w + OFF_CRZ);
  float* cni = (float*)(w + OFF_CNI);
  float* cnh = (float*)(w + OFF_CNH);
  float* wrz = (float*)(w + OFF_WRZ);
  float* wni = (float*)(w + OFF_WNI);
  float* wnh = (float*)(w + OFF_WNH);
  unsigned* cnt = (unsigned*)(w + OFF_CNT);
  uint16_t* feats = (uint16_t*)(w + OFF_FEATS);
  uint16_t* xwb   = (uint16_t*)(w + OFF_XW);
  uint16_t* Hb    = (uint16_t*)(w + OFF_H);

  // >64KB dynamic LDS kernels need the attribute; idempotent, host-side only.
  (void)hipFuncSetAttribute((const void*)k_char, hipFuncAttributeMaxDynamicSharedMemorySize, 126208);
  (void)hipFuncSetAttribute((const void*)k_gru,  hipFuncAttributeMaxDynamicSharedMemorySize, 99840);

  k_prep<<<512, 256, 0, stream>>>(cWi, cWh, gWi, gWh, cembw, cbi, cbh, gbi, gbh,
                                  o_cWi, o_cWh, o_gWi, o_gWh, o_cemb,
                                  crz, cni, cnh, wrz, wni, wnh, cnt);
  k_emb<<<8192, 256, 0, stream>>>(x, embw, feats);
  k_char<<<512, 256, 126208, stream>>>(xch, o_cemb, o_cWi, o_cWh, crz, cni, cnh, feats);
  k_gemm_xw<<<3072, 256, 0, stream>>>(feats, o_gWi, xwb);
  k_gru<<<128, 64, 99840, stream>>>(xwb, o_gWh, wrz, wni, wnh, Hb, cnt);
  k_cls<<<2560, 256, 0, stream>>>(Hb, clsW, clsb, out);
}

// Round 4
// 2120.775 us; speedup vs baseline: 2.0943x; 1.3019x over previous
//
#include <hip/hip_runtime.h>
#include <cstdio>
#include <cstdint>

// ---------- types / helpers ----------
typedef __attribute__((ext_vector_type(8))) short short8;   // 8 bf16 (4 VGPRs)
typedef __attribute__((ext_vector_type(4))) float f32x4;    // MFMA 16x16 acc

__device__ __forceinline__ f32x4 MFMA16(short8 a, short8 b, f32x4 c) {
  return __builtin_amdgcn_mfma_f32_16x16x32_bf16(a, b, c, 0, 0, 0);
}
__device__ __forceinline__ float bf2f(uint16_t u) {
  union { uint32_t u; float f; } v; v.u = ((uint32_t)u) << 16; return v.f;
}
__device__ __forceinline__ uint16_t f2bf(float f) {
  union { float f; uint32_t u; } v; v.f = f;
  uint32_t r = v.u + 0x7fffu + ((v.u >> 16) & 1u);  // RNE
  return (uint16_t)(r >> 16);
}
__device__ __forceinline__ float fsig(float x) { return 1.0f / (1.0f + __expf(-x)); }
__device__ __forceinline__ float ftanh_(float x) { return 2.0f / (1.0f + __expf(-2.0f * x)) - 1.0f; }

// Problem dims
// B=128 S=256 L=16, EMB=256 HID=512, CEMB=64 CHID=128, NCLS=20
// word rows n = t*128 + b  (matches x_chars.reshape(S*B, L))

// ---------- ws layout (bytes) ----------
#define OFF_CWI   0u            // char_Wi bf16 [384][64]
#define OFF_CWH   49152u        // char_Wh bf16 [384][128]
#define OFF_GWI   147456u       // gru_Wi  bf16 [1536][384]
#define OFF_GWH   1327104u      // gru_Wh  bf16 [1536][512]
#define OFF_CEMB  2899968u      // char_emb bf16 [128][64]
#define OFF_CRZ   2916352u      // f32 [256]  char bi+bh (r,z)
#define OFF_CNI   2917376u      // f32 [128]  char bi (n)
#define OFF_CNH   2917888u      // f32 [128]  char bh (n)
#define OFF_WRZ   2918400u      // f32 [1024] gru bi+bh (r,z)
#define OFF_WNI   2922496u      // f32 [512]  gru bi (n)
#define OFF_WNH   2924544u      // f32 [512]  gru bh (n)
#define OFF_CNT   2926592u      // 32KB sync region (8192 uints):
                                //   [wgid*32]       arrival flags, 128 WGs, 128B apart
                                //   [gb*64]  (fallback counters share low region? NO ->)
                                //   [4096]          topology rendezvous counter
                                //   [4224+x*32]     per-XCD claim counters (8, 128B apart)
                                //   [4608+gb*32]    fallback step counters (8, 128B apart)
#define OFF_FEATS 3145728u      // bf16 [32768][384]
#define OFF_XW    28311552u     // bf16 [32768][1536]
#define OFF_H     128974848u    // bf16 [32768][512]  (= [256][128][512])
#define WS_NEEDED 145752064ull

// ---------- K0: weight convert + bias fuse + counter zero ----------
__global__ void k_prep(const float* __restrict__ cWi, const float* __restrict__ cWh,
                       const float* __restrict__ gWi, const float* __restrict__ gWh,
                       const float* __restrict__ cemb,
                       const float* __restrict__ cbi, const float* __restrict__ cbh,
                       const float* __restrict__ gbi, const float* __restrict__ gbh,
                       uint16_t* o_cWi, uint16_t* o_cWh, uint16_t* o_gWi, uint16_t* o_gWh,
                       uint16_t* o_cemb, float* o_crz, float* o_cni, float* o_cnh,
                       float* o_wrz, float* o_wni, float* o_wnh, unsigned* cnt)
{
  int g = blockIdx.x * 256 + threadIdx.x;
  int st = gridDim.x * 256;
  for (int i = g; i < 24576;  i += st) o_cWi[i] = f2bf(cWi[i]);
  for (int i = g; i < 49152;  i += st) o_cWh[i] = f2bf(cWh[i]);
  for (int i = g; i < 589824; i += st) o_gWi[i] = f2bf(gWi[i]);
  for (int i = g; i < 786432; i += st) o_gWh[i] = f2bf(gWh[i]);
  for (int i = g; i < 8192;   i += st) o_cemb[i] = f2bf(cemb[i]);
  for (int i = g; i < 256;  i += st) o_crz[i] = cbi[i] + cbh[i];
  for (int i = g; i < 128;  i += st) { o_cni[i] = cbi[256 + i]; o_cnh[i] = cbh[256 + i]; }
  for (int i = g; i < 1024; i += st) o_wrz[i] = gbi[i] + gbh[i];
  for (int i = g; i < 512;  i += st) { o_wni[i] = gbi[1024 + i]; o_wnh[i] = gbh[1024 + i]; }
  for (int i = g; i < 8192; i += st) cnt[i] = 0u;   // whole 32KB sync region
}

// ---------- K2: word embedding gather -> feats[:, 0:256] ----------
__global__ void k_emb(const int* __restrict__ x, const float* __restrict__ embw,
                      uint16_t* __restrict__ feats)
{
  int n = blockIdx.x * 4 + (threadIdx.x >> 6);   // word row, n = t*128 + b
  int lane = threadIdx.x & 63;
  int t = n >> 7, b = n & 127;
  int wid = x[b * 256 + t];
  float4 v = *(const float4*)(embw + (size_t)wid * 256 + lane * 4);
  uint16_t* dst = feats + (size_t)n * 384 + lane * 4;
  dst[0] = f2bf(v.x); dst[1] = f2bf(v.y); dst[2] = f2bf(v.z); dst[3] = f2bf(v.w);
}

// ---------- K1: char GRU (batch-parallel, MFMA) -> feats[:, 256:384] ----------
// Grid 512 x 256 thr (4 waves, 16 words/wave). LDS: Wh[384][136] + ids[64][17] + h[64][136]
__global__ __launch_bounds__(256, 1) void k_char(
    const int* __restrict__ xch, const uint16_t* __restrict__ cembw,
    const uint16_t* __restrict__ cWi, const uint16_t* __restrict__ cWh,
    const float* __restrict__ crz, const float* __restrict__ cni,
    const float* __restrict__ cnh, uint16_t* __restrict__ feats)
{
  extern __shared__ char lds[];
  uint16_t* WhL = (uint16_t*)lds;                    // [384][136] bf16, 104448 B
  int*      idsL = (int*)(lds + 104448);             // [64][17], 4352 B
  uint16_t* hL  = (uint16_t*)(lds + 104448 + 4352);  // [64][136], 17408 B
  const int tid = threadIdx.x;
  const int wbase = blockIdx.x * 64;

  for (int i = tid; i < 384 * 16; i += 256) {
    int row = i >> 4, ch = i & 15;
    *(uint4*)(WhL + row * 136 + ch * 8) = *(const uint4*)(cWh + row * 128 + ch * 8);
  }
  for (int i = tid; i < 64 * 16; i += 256) {
    int w0 = i >> 4, p = i & 15;
    idsL[w0 * 17 + p] = xch[(wbase + w0) * 16 + p];
  }
  for (int i = tid; i < 64 * 136 / 2; i += 256) ((unsigned*)hL)[i] = 0u;
  __syncthreads();

  const int wv = tid >> 6, lane = tid & 63;
  const int q = lane >> 4, c = lane & 15;
  float br_[8], bz_[8], bni_[8], bnh_[8];
#pragma unroll
  for (int jb = 0; jb < 8; ++jb) {
    int j = jb * 16 + c;
    br_[jb] = crz[j]; bz_[jb] = crz[128 + j]; bni_[jb] = cni[j]; bnh_[jb] = cnh[j];
  }
  const int lwA = wv * 16 + c;        // word row for A-operand (m = lane&15)
  const int lwD = wv * 16 + q * 4;    // D rows base (+reg)

  for (int t = 0; t < 16; ++t) {
    f32x4 aRZ[16], aXN[8], aGN[8];
#pragma unroll
    for (int i = 0; i < 16; ++i) aRZ[i] = (f32x4)0.0f;
#pragma unroll
    for (int i = 0; i < 8; ++i) { aXN[i] = (f32x4)0.0f; aGN[i] = (f32x4)0.0f; }

    // xw contribution: cemb[word,t,:] @ Wi^T   (K=64)
    int id = idsL[lwA * 17 + t];
    const uint16_t* cerow = cembw + id * 64;
    short8 Ae0 = *(const short8*)(cerow + q * 8);
    short8 Ae1 = *(const short8*)(cerow + 32 + q * 8);
#pragma unroll
    for (int tl = 0; tl < 24; ++tl) {
      const uint16_t* wr = cWi + (tl * 16 + c) * 64 + q * 8;
      short8 B0 = *(const short8*)(wr);
      short8 B1 = *(const short8*)(wr + 32);
      if (tl < 16) { aRZ[tl] = MFMA16(Ae0, B0, aRZ[tl]); aRZ[tl] = MFMA16(Ae1, B1, aRZ[tl]); }
      else { aXN[tl - 16] = MFMA16(Ae0, B0, aXN[tl - 16]); aXN[tl - 16] = MFMA16(Ae1, B1, aXN[tl - 16]); }
    }
    // gh contribution: h @ Wh^T   (K=128); h=0 at t=0 is harmless
    short8 Ah[4];
#pragma unroll
    for (int kt = 0; kt < 4; ++kt) Ah[kt] = *(const short8*)(hL + lwA * 136 + kt * 32 + q * 8);
#pragma unroll
    for (int tl = 0; tl < 24; ++tl) {
#pragma unroll
      for (int kt = 0; kt < 4; ++kt) {
        short8 Bw = *(const short8*)(WhL + (tl * 16 + c) * 136 + kt * 32 + q * 8);
        if (tl < 16) aRZ[tl] = MFMA16(Ah[kt], Bw, aRZ[tl]);
        else aGN[tl - 16] = MFMA16(Ah[kt], Bw, aGN[tl - 16]);
      }
    }
    // gates + h update (f32)
#pragma unroll
    for (int jb = 0; jb < 8; ++jb) {
      int j = jb * 16 + c;
#pragma unroll
      for (int rg = 0; rg < 4; ++rg) {
        float r = fsig(aRZ[jb][rg] + br_[jb]);
        float z = fsig(aRZ[8 + jb][rg] + bz_[jb]);
        float n = ftanh_(aXN[jb][rg] + bni_[jb] + r * (aGN[jb][rg] + bnh_[jb]));
        int hoff = (lwD + rg) * 136 + j;
        float hold = bf2f(hL[hoff]);
        hL[hoff] = f2bf((1.0f - z) * n + z * hold);
      }
    }
  }
  __syncthreads();
  for (int i = tid; i < 64 * 128; i += 256) {
    int w0 = i >> 7, col = i & 127;
    feats[(size_t)(wbase + w0) * 384 + 256 + col] = hL[w0 * 136 + col];
  }
}

// ---------- K3: xw = feats @ gru_Wi^T  (M=32768, N=1536, K=384) ----------
__global__ __launch_bounds__(256) void k_gemm_xw(
    const uint16_t* __restrict__ A, const uint16_t* __restrict__ Bm,
    uint16_t* __restrict__ C)
{
  __shared__ uint16_t AL[128 * 40];
  __shared__ uint16_t BL[128 * 40];
  const int tid = threadIdx.x;
  const int bm = blockIdx.x & 255, bn = blockIdx.x >> 8;
  const int m0 = bm * 128, n0 = bn * 128;
  const int wv = tid >> 6, lane = tid & 63, q = lane >> 4, c = lane & 15;
  const int vm = (wv >> 1) * 64, vn = (wv & 1) * 64;
  f32x4 acc[4][4];
#pragma unroll
  for (int mt = 0; mt < 4; ++mt)
#pragma unroll
    for (int nt = 0; nt < 4; ++nt) acc[mt][nt] = (f32x4)0.0f;

  for (int k0 = 0; k0 < 384; k0 += 32) {
    __syncthreads();
    for (int i2 = tid; i2 < 512; i2 += 256) {
      int row = i2 >> 2, cc = i2 & 3;
      *(uint4*)(AL + row * 40 + cc * 8) = *(const uint4*)(A + (size_t)(m0 + row) * 384 + k0 + cc * 8);
      *(uint4*)(BL + row * 40 + cc * 8) = *(const uint4*)(Bm + (size_t)(n0 + row) * 384 + k0 + cc * 8);
    }
    __syncthreads();
    short8 af[4], bfr[4];
#pragma unroll
    for (int mt = 0; mt < 4; ++mt) af[mt] = *(const short8*)(AL + (vm + mt * 16 + c) * 40 + q * 8);
#pragma unroll
    for (int nt = 0; nt < 4; ++nt) bfr[nt] = *(const short8*)(BL + (vn + nt * 16 + c) * 40 + q * 8);
#pragma unroll
    for (int mt = 0; mt < 4; ++mt)
#pragma unroll
      for (int nt = 0; nt < 4; ++nt) acc[mt][nt] = MFMA16(af[mt], bfr[nt], acc[mt][nt]);
  }
#pragma unroll
  for (int mt = 0; mt < 4; ++mt)
#pragma unroll
    for (int nt = 0; nt < 4; ++nt)
#pragma unroll
      for (int rg = 0; rg < 4; ++rg) {
        int m = m0 + vm + mt * 16 + q * 4 + rg;
        int n = n0 + vn + nt * 16 + c;
        C[(size_t)m * 1536 + n] = f2bf(acc[mt][nt][rg]);
      }
}

// ---------- K4: word GRU, persistent, 128 WGs x 64 thr ----------
// Topology discovery as R3 (XCD-local groups of 16 when placement allows).
// Barrier (fast path): all-to-all arrival FLAGS, one 128B line per WG.
//   arrive: vmcnt(0) store-drain, then plain agent store flag[me]=t+1 (no RMW).
//   detect: lane (i&15) polls flag i of the group; __all(v >= t+1). No same-line
//   RMW-vs-read contention; reads of a shared line serve concurrently.
// Fallback (placement not XCD-local): R3 fenced counter barrier.
__global__ __launch_bounds__(64, 1) void k_gru(
    const uint16_t* __restrict__ xw, const uint16_t* __restrict__ gWh,
    const float* __restrict__ wrz, const float* __restrict__ wni,
    const float* __restrict__ wnh, uint16_t* __restrict__ H,
    unsigned* __restrict__ cnt)
{
  extern __shared__ char lds[];
  uint16_t* WhL = (uint16_t*)lds;   // [96][520] = 99840 B
  const int tid = threadIdx.x;

  // ---- Phase A: topology discovery (one rendezvous of all 128 WGs) ----
  unsigned xcd;
  asm volatile("s_getreg_b32 %0, hwreg(HW_REG_XCC_ID, 0, 4)" : "=s"(xcd));
  unsigned* rdv = cnt + 4096;             // rendezvous counter
  int myslot = 0;
  if (tid == 0) {
    myslot = (int)__hip_atomic_fetch_add(cnt + 4224 + xcd * 32, 1u, __ATOMIC_RELAXED, __HIP_MEMORY_SCOPE_AGENT);
    __hip_atomic_fetch_add(rdv, 1u, __ATOMIC_RELEASE, __HIP_MEMORY_SCOPE_AGENT);
  }
  myslot = __shfl(myslot, 0);
  {
    int sp = 0;
    while (__hip_atomic_load(rdv, __ATOMIC_ACQUIRE, __HIP_MEMORY_SCOPE_AGENT) < 128u) {
      __builtin_amdgcn_s_sleep(1);
      if (++sp > 10000000) break;
    }
  }
  unsigned G = 0, base = 0;
#pragma unroll
  for (int x2 = 0; x2 < 8; ++x2) {
    unsigned v = __hip_atomic_load(cnt + 4224 + x2 * 32, __ATOMIC_RELAXED, __HIP_MEMORY_SCOPE_AGENT) >> 4;
    if ((unsigned)x2 < xcd) base += v;
    G += v;
  }
  bool fastp; int gb, gc;
  if (G == 8u) { fastp = true; gb = (int)(base + ((unsigned)myslot >> 4)); gc = myslot & 15; }
  else         { fastp = false; gb = blockIdx.x & 7; gc = blockIdx.x >> 3; }

  const int m0 = gb * 16, j0 = gc * 32;
  unsigned* gflag  = cnt + ((gb * 16) << 5);          // group's 16 flags, 128B apart
  unsigned* myflag = gflag + (gc << 5);
  unsigned* myCnt  = cnt + 4608 + (gb << 5);          // fallback counter

  for (int i = tid; i < 96 * 64; i += 64) {
    int row = i >> 6, ch = i & 63;
    int gr = (row < 32) ? (j0 + row) : (row < 64) ? (512 + j0 + row - 32) : (1024 + j0 + row - 64);
    *(uint4*)(WhL + row * 520 + ch * 8) = *(const uint4*)(gWh + (size_t)gr * 512 + ch * 8);
  }
  const int q = tid >> 4, c = tid & 15;
  const int j1 = j0 + c, j2 = j0 + 16 + c;
  const float br0 = wrz[j1], br1 = wrz[j2];
  const float bz0 = wrz[512 + j1], bz1 = wrz[512 + j2];
  const float bi0 = wni[j1], bi1 = wni[j2];
  const float bh0 = wnh[j1], bh1 = wnh[j2];
  __syncthreads();

  // xw register prefetch for step 0; h_old kept in registers
  uint16_t pf[4][6];
  {
    const uint16_t* xwt = xw + (size_t)m0 * 1536;
#pragma unroll
    for (int rg = 0; rg < 4; ++rg) {
      const uint16_t* rowp = xwt + (q * 4 + rg) * 1536;
      pf[rg][0] = rowp[j1];        pf[rg][1] = rowp[j2];
      pf[rg][2] = rowp[512 + j1];  pf[rg][3] = rowp[512 + j2];
      pf[rg][4] = rowp[1024 + j1]; pf[rg][5] = rowp[1024 + j2];
    }
  }
  float hold1[4] = {0.f, 0.f, 0.f, 0.f}, hold2[4] = {0.f, 0.f, 0.f, 0.f};

  for (int t = 0; t < 256; ++t) {
    f32x4 acc[6];
    float xn1[4], xn2[4];
#pragma unroll
    for (int rg = 0; rg < 4; ++rg) {
      acc[0][rg] = bf2f(pf[rg][0]); acc[1][rg] = bf2f(pf[rg][1]);
      acc[2][rg] = bf2f(pf[rg][2]); acc[3][rg] = bf2f(pf[rg][3]);
      acc[4][rg] = 0.0f; acc[5][rg] = 0.0f;
      xn1[rg] = bf2f(pf[rg][4]); xn2[rg] = bf2f(pf[rg][5]);
    }
    if (t > 0) {
      const uint16_t* hp = H + (size_t)((t - 1) * 128 + m0) * 512 + c * 512;
#pragma unroll 4
      for (int kt = 0; kt < 16; ++kt) {
        short8 a = *(const short8*)(hp + kt * 32 + q * 8);
#pragma unroll
        for (int tl = 0; tl < 6; ++tl) {
          short8 b = *(const short8*)(WhL + (tl * 16 + c) * 520 + kt * 32 + q * 8);
          acc[tl] = MFMA16(a, b, acc[tl]);
        }
      }
    }
    uint16_t* hcur = H + (size_t)(t * 128 + m0) * 512;
#pragma unroll
    for (int rg = 0; rg < 4; ++rg) {
      int m = q * 4 + rg;
      float r0 = fsig(acc[0][rg] + br0);
      float z0 = fsig(acc[2][rg] + bz0);
      float n0 = ftanh_(xn1[rg] + bi0 + r0 * (acc[4][rg] + bh0));
      float h0 = (1.0f - z0) * n0 + z0 * hold1[rg];
      hold1[rg] = h0;
      hcur[m * 512 + j1] = f2bf(h0);
      float r1 = fsig(acc[1][rg] + br1);
      float z1 = fsig(acc[3][rg] + bz1);
      float n1 = ftanh_(xn2[rg] + bi1 + r1 * (acc[5][rg] + bh1));
      float h1 = (1.0f - z1) * n1 + z1 * hold2[rg];
      hold2[rg] = h1;
      hcur[m * 512 + j2] = f2bf(h1);
    }
    if (t == 255) break;   // no barrier after final step
    const unsigned tgt = (unsigned)(t + 1);
    if (fastp) {
      // arrive: drain H stores to (XCD-local) L2, then publish flag (plain store, own line)
      asm volatile("s_waitcnt vmcnt(0)" ::: "memory");
      if (tid == 0)
        __hip_atomic_store(myflag, tgt, __ATOMIC_RELAXED, __HIP_MEMORY_SCOPE_AGENT);
      // prefetch xw(t+1): overlaps the spin
      {
        const uint16_t* xwn = xw + (size_t)((t + 1) * 128 + m0) * 1536;
#pragma unroll
        for (int rg = 0; rg < 4; ++rg) {
          const uint16_t* rowp = xwn + (q * 4 + rg) * 1536;
          pf[rg][0] = rowp[j1];        pf[rg][1] = rowp[j2];
          pf[rg][2] = rowp[512 + j1];  pf[rg][3] = rowp[512 + j2];
          pf[rg][4] = rowp[1024 + j1]; pf[rg][5] = rowp[1024 + j2];
        }
      }
      // detect: lane (tid&15) polls flag (tid&15); all 16 flags checked per round
      unsigned* watch = gflag + ((tid & 15) << 5);
      int sp = 0;
      for (;;) {
        unsigned v = __hip_atomic_load(watch, __ATOMIC_RELAXED, __HIP_MEMORY_SCOPE_AGENT);
        if (__all((int)(v >= tgt))) break;
        if (++sp > 2000000) break;   // safety: terminate over hang
      }
      asm volatile("" ::: "memory");
    } else {
      // prefetch first (fallback keeps R3 ordering)
      {
        const uint16_t* xwn = xw + (size_t)((t + 1) * 128 + m0) * 1536;
#pragma unroll
        for (int rg = 0; rg < 4; ++rg) {
          const uint16_t* rowp = xwn + (q * 4 + rg) * 1536;
          pf[rg][0] = rowp[j1];        pf[rg][1] = rowp[j2];
          pf[rg][2] = rowp[512 + j1];  pf[rg][3] = rowp[512 + j2];
          pf[rg][4] = rowp[1024 + j1]; pf[rg][5] = rowp[1024 + j2];
        }
      }
      __threadfence();
      if (tid == 0) __hip_atomic_fetch_add(myCnt, 1u, __ATOMIC_RELAXED, __HIP_MEMORY_SCOPE_AGENT);
      const unsigned target = tgt * 16u;  // 16 WGs per batch group
      int sp = 0;
      while (__hip_atomic_load(myCnt, __ATOMIC_RELAXED, __HIP_MEMORY_SCOPE_AGENT) < target) {
        __builtin_amdgcn_s_sleep(1);
        if (++sp > 2000000) break;   // safety
      }
      __threadfence();
    }
  }
}

// ---------- K5: classifier pred[b,t,c] = H[t,b,:] . cls_W[c,:] + cls_b[c] ----------
__global__ void k_cls(const uint16_t* __restrict__ H, const float* __restrict__ W,
                      const float* __restrict__ bb, float* __restrict__ out)
{
  int g = blockIdx.x * 256 + threadIdx.x;   // 655360 = 32768 rows * 20
  int c = g % 20, row = g / 20;
  int t = row >> 7, b = row & 127;
  const uint16_t* hp = H + (size_t)row * 512;
  const float* wp = W + c * 512;
  float acc = 0.0f;
  for (int i = 0; i < 512; i += 8) {
    uint4 hv = *(const uint4*)(hp + i);
    float4 w0 = *(const float4*)(wp + i);
    float4 w1 = *(const float4*)(wp + i + 4);
    acc += bf2f((uint16_t)hv.x) * w0.x + bf2f((uint16_t)(hv.x >> 16)) * w0.y
         + bf2f((uint16_t)hv.y) * w0.z + bf2f((uint16_t)(hv.y >> 16)) * w0.w
         + bf2f((uint16_t)hv.z) * w1.x + bf2f((uint16_t)(hv.z >> 16)) * w1.y
         + bf2f((uint16_t)hv.w) * w1.z + bf2f((uint16_t)(hv.w >> 16)) * w1.w;
  }
  out[((size_t)b * 256 + t) * 20 + c] = acc + bb[c];
}

// ---------- launch ----------
extern "C" void kernel_launch(void* const* d_in, const int* in_sizes, int n_in,
                              void* d_out, int out_size, void* d_ws, size_t ws_size,
                              hipStream_t stream) {
  (void)in_sizes; (void)n_in; (void)out_size;
  const int*   x     = (const int*)d_in[0];
  const int*   xch   = (const int*)d_in[1];
  const float* embw  = (const float*)d_in[2];
  const float* cembw = (const float*)d_in[3];
  const float* cWi   = (const float*)d_in[4];
  const float* cWh   = (const float*)d_in[5];
  const float* cbi   = (const float*)d_in[6];
  const float* cbh   = (const float*)d_in[7];
  const float* gWi   = (const float*)d_in[8];
  const float* gWh   = (const float*)d_in[9];
  const float* gbi   = (const float*)d_in[10];
  const float* gbh   = (const float*)d_in[11];
  const float* clsW  = (const float*)d_in[12];
  const float* clsb  = (const float*)d_in[13];
  float* out = (float*)d_out;
  char* w = (char*)d_ws;

  if (ws_size < WS_NEEDED) { fprintf(stderr, "ws too small: %zu < %llu\n", ws_size, WS_NEEDED); return; }

  uint16_t* o_cWi  = (uint16_t*)(w + OFF_CWI);
  uint16_t* o_cWh  = (uint16_t*)(w + OFF_CWH);
  uint16_t* o_gWi  = (uint16_t*)(w + OFF_GWI);
  uint16_t* o_gWh  = (uint16_t*)(w + OFF_GWH);
  uint16_t* o_cemb = (uint16_t*)(w + OFF_CEMB);
  float* crz = (float*)(w + OFF_CRZ);
  float* cni = (float*)(w + OFF_CNI);
  float* cnh = (float*)(w + OFF_CNH);
  float* wrz = (float*)(w + OFF_WRZ);
  float* wni = (float*)(w + OFF_WNI);
  float* wnh = (float*)(w + OFF_WNH);
  unsigned* cnt = (unsigned*)(w + OFF_CNT);
  uint16_t* feats = (uint16_t*)(w + OFF_FEATS);
  uint16_t* xwb   = (uint16_t*)(w + OFF_XW);
  uint16_t* Hb    = (uint16_t*)(w + OFF_H);

  // >64KB dynamic LDS kernels need the attribute; idempotent, host-side only.
  (void)hipFuncSetAttribute((const void*)k_char, hipFuncAttributeMaxDynamicSharedMemorySize, 126208);
  (void)hipFuncSetAttribute((const void*)k_gru,  hipFuncAttributeMaxDynamicSharedMemorySize, 99840);

  k_prep<<<512, 256, 0, stream>>>(cWi, cWh, gWi, gWh, cembw, cbi, cbh, gbi, gbh,
                                  o_cWi, o_cWh, o_gWi, o_gWh, o_cemb,
                                  crz, cni, cnh, wrz, wni, wnh, cnt);
  k_emb<<<8192, 256, 0, stream>>>(x, embw, feats);
  k_char<<<512, 256, 126208, stream>>>(xch, o_cemb, o_cWi, o_cWh, crz, cni, cnh, feats);
  k_gemm_xw<<<3072, 256, 0, stream>>>(feats, o_gWi, xwb);
  k_gru<<<128, 64, 99840, stream>>>(xwb, o_gWh, wrz, wni, wnh, Hb, cnt);
  k_cls<<<2560, 256, 0, stream>>>(Hb, clsW, clsb, out);
}